// Round 3
// baseline (21088.406 us; speedup 1.0000x reference)
//
#include <hip/hip_runtime.h>

#define SEQ  4096
#define NB   64
#define NI   64
#define NH   256

typedef short  bf16x8 __attribute__((ext_vector_type(8)));
typedef short  bf16x4 __attribute__((ext_vector_type(4)));
typedef float  f32x4  __attribute__((ext_vector_type(4)));

__device__ __forceinline__ unsigned short f2bf(float f) {
    union { float f; unsigned u; } v; v.f = f;
    return (unsigned short)((v.u + 0x7fffu + ((v.u >> 16) & 1u)) >> 16);
}
__device__ __forceinline__ float bflo(int p) {
    union { int i; float f; } u; u.i = p << 16; return u.f;
}
__device__ __forceinline__ float bfhi(int p) {
    union { int i; float f; } u; u.i = p & 0xffff0000; return u.f;
}
__device__ __forceinline__ float fast_rcp(float x) { return __builtin_amdgcn_rcpf(x); }
__device__ __forceinline__ float sigm(float x) { return fast_rcp(1.f + __expf(-x)); }
// clamp-free tanh: 2/(1+e^{-2y}) - 1.  y->+inf: e->0 -> 1; y->-inf: e->inf -> rcp->0 -> -1.
__device__ __forceinline__ float tanh_(float y) {
    float e = __expf(-2.f * y);
    return fmaf(2.f, fast_rcp(1.f + e), -1.f);
}
__device__ __forceinline__ f32x4 mfma16(bf16x8 a, bf16x8 b, f32x4 c) {
    return __builtin_amdgcn_mfma_f32_16x16x32_bf16(a, b, c, 0, 0, 0);
}
__device__ __forceinline__ bf16x8 ldfrag(const float* p) {
    float4 a = *(const float4*)p;
    float4 b = *(const float4*)(p + 4);
    bf16x8 r;
    r[0] = (short)f2bf(a.x); r[1] = (short)f2bf(a.y);
    r[2] = (short)f2bf(a.z); r[3] = (short)f2bf(a.w);
    r[4] = (short)f2bf(b.x); r[5] = (short)f2bf(b.y);
    r[6] = (short)f2bf(b.z); r[7] = (short)f2bf(b.w);
    return r;
}

// ============ xg precompute: unchanged ======================================
__global__ __launch_bounds__(1024) void xg_pre(
        const float* __restrict__ x, const float* __restrict__ w_ih,
        const float* __restrict__ b_ih, const float* __restrict__ b_hh,
        short* __restrict__ xg, size_t plane, int t0, int ns)
{
    const int tid = threadIdx.x, wv = tid >> 6, lane = tid & 63;
    const int nn = lane & 15, q = lane >> 4;
    const int jb = wv;

    bf16x8 w[3][2];
    float bias[3];
    #pragma unroll
    for (int g = 0; g < 3; ++g) {
        const int row = g * NH + jb * 16 + nn;
        w[g][0] = ldfrag(w_ih + row * NI + q * 8);
        w[g][1] = ldfrag(w_ih + row * NI + 32 + q * 8);
        bias[g] = b_ih[row] + (g < 2 ? b_hh[row] : 0.f);
    }

    const int NT = ns * 4;
    for (int rt = blockIdx.x; rt < NT; rt += gridDim.x) {
        const float* xr = x + ((size_t)t0 * NB + (size_t)rt * 16 + nn) * NI + q * 8;
        bf16x8 a0 = ldfrag(xr);
        bf16x8 a1 = ldfrag(xr + 32);
        #pragma unroll
        for (int g = 0; g < 3; ++g) {
            f32x4 acc = {0.f, 0.f, 0.f, 0.f};
            acc = mfma16(a0, w[g][0], acc);
            acc = mfma16(a1, w[g][1], acc);
            bf16x4 v;
            #pragma unroll
            for (int m = 0; m < 4; ++m) v[m] = (short)f2bf(acc[m] + bias[g]);
            *(bf16x4*)(xg + (size_t)g * plane +
                       (((size_t)rt * 16 + jb) * 64 + lane) * 4) = v;
        }
    }
}

// ============ recurrent kernel ==============================================
// Round-0 16-wave structure (proven 4353us) with the n-gate weights moved
// from LDS to registers: all 3 gates' W_hh frags = 96 regs/wave (expect
// ~32 VGPR + 96 AGPR; MFMA reads B from AGPR directly on gfx950).
// This halves the binding LDS read traffic (256 -> 136 KB/step/CU): the
// wn tile was constant but re-read every step by every wave.
// xg loads stay at loop top, consumed AFTER the MFMA chain (round-2 lesson:
// folding them into MFMA C-init moves the vmcnt wait before the MFMA phase
// and exposes the load latency). Safe round-2 items kept: clamp-free tanh,
// an C-init = bhn.
// grid 4 x 1024 threads (16 waves, 4 waves/SIMD).
// LDS: abuf 16K | fcwl 8K | oring 4K = 28 KB.
__global__ __launch_bounds__(1024, 4) void gru_rec(
        const short* __restrict__ xg, size_t plane,
        const float* __restrict__ w_hh,
        const float* __restrict__ b_hh,
        const float* __restrict__ fc_w,
        const float* __restrict__ fc_b,
        float* __restrict__ out,
        float* __restrict__ hcar,
        int t0, int ns)
{
    __shared__ short abuf[8192];     // h staging, 2 x 8 chunks x 512
    __shared__ short fcwl[4096];     // fc_w B-frags (col 0 only), 8 x 512
    __shared__ float oring[1024];    // out ring, 2 x 32 steps x 16 batch

    const int tid = threadIdx.x, wv = tid >> 6, lane = tid & 63;
    const int nn = lane & 15, q = lane >> 4;
    const int bc = blockIdx.x, bbase = bc * 16;

    // ---- one-time staging: all three gates' weights in registers ----
    bf16x8 wr[8], wz[8], wn[8];
    #pragma unroll
    for (int c = 0; c < 8; ++c)
        wr[c] = ldfrag(w_hh + (0 * NH + wv * 16 + nn) * NH + c * 32 + q * 8);
    #pragma unroll
    for (int c = 0; c < 8; ++c)
        wz[c] = ldfrag(w_hh + (1 * NH + wv * 16 + nn) * NH + c * 32 + q * 8);
    #pragma unroll
    for (int c = 0; c < 8; ++c)
        wn[c] = ldfrag(w_hh + (2 * NH + wv * 16 + nn) * NH + c * 32 + q * 8);
    if (wv < 8) {                    // fc B-frag: col nn==0 = fc_w, else 0
        bf16x8 f = 0;
        if (nn == 0) f = ldfrag(fc_w + wv * 32 + q * 8);
        *(bf16x8*)(fcwl + wv * 512 + lane * 8) = f;
    }
    const float bhn = b_hh[2 * NH + wv * 16 + nn];
    const float fcb = fc_b[0];

    // ---- h init ----
    f32x4 hp = {0.f, 0.f, 0.f, 0.f};
    if (t0 == 0) {
        ((int4*)abuf)[tid & 511] = make_int4(0, 0, 0, 0);   // first 512 tids suffice
    } else {
        #pragma unroll
        for (int m = 0; m < 4; ++m)
            hp[m] = hcar[(size_t)(bbase + q * 4 + m) * NH + wv * 16 + nn];
        const int f = tid * 4, b = f >> 8, k0 = f & 255;
        float4 v = *(const float4*)(hcar + (size_t)(bbase + b) * NH + k0);
        bf16x4 s; s[0] = (short)f2bf(v.x); s[1] = (short)f2bf(v.y);
        s[2] = (short)f2bf(v.z); s[3] = (short)f2bf(v.w);
        *(bf16x4*)(abuf + (k0 >> 5) * 512 + (((k0 >> 3) & 3) * 16 + b) * 8 + (k0 & 7)) = s;
    }

    const int j = wv * 16 + nn;
    const int koff = (j >> 5) * 512 + ((j >> 3) & 3) * 128 + (j & 7) + q * 32;
    const short* xgp = xg + ((size_t)(bc * 16 + wv) * 64 + lane) * 4;
    __syncthreads();

    for (int t = 0; t < ns; ++t) {
        const int cur = t & 1, nxt = cur ^ 1;

        // xg loads issued here, consumed after the MFMA chain (latency hidden)
        int2 gx = *(const int2*)(xgp);
        int2 gz = *(const int2*)(xgp + plane);
        int2 gn = *(const int2*)(xgp + 2 * plane);
        xgp += 16384;

        // out flush, once per 32 steps (slots all >=1 barrier old)
        if ((t & 31) == 1 && t >= 33 && tid < 512) {
            const int s0 = t - 33;
            out[((size_t)(t0 + s0 + (tid >> 4))) * NB + bbase + (tid & 15)] =
                oring[(((s0 >> 5) & 1) << 9) + (tid >> 4) * 16 + (tid & 15)];
        }

        const bool isfc = (t > 0) && (wv == (t & 15));
        f32x4 ar = {0.f,0.f,0.f,0.f}, az = {0.f,0.f,0.f,0.f};
        f32x4 an = { bhn, bhn, bhn, bhn };   // b_hh(n) folded into C-init
        f32x4 afc = {0.f,0.f,0.f,0.f};
        const short* ab = abuf + cur * 4096;
        #pragma unroll
        for (int c = 0; c < 8; ++c) {
            bf16x8 av = *(const bf16x8*)(ab + c * 512 + lane * 8);
            ar = mfma16(av, wr[c], ar);
            az = mfma16(av, wz[c], az);
            an = mfma16(av, wn[c], an);
            if (isfc) {   // rotating wave: FC(h_{t-1}) rides on the same av
                bf16x8 ff = *(const bf16x8*)(fcwl + c * 512 + lane * 8);
                afc = mfma16(av, ff, afc);
            }
        }
        if (isfc && nn == 0) {
            const int s = t - 1;
            f32x4 v;
            #pragma unroll
            for (int m = 0; m < 4; ++m) v[m] = afc[m] + fcb;
            *(f32x4*)(oring + (((s >> 5) & 1) << 9) + ((s & 31) << 4) + q * 4) = v;
        }

        const float xr4[4] = { bflo(gx.x), bfhi(gx.x), bflo(gx.y), bfhi(gx.y) };
        const float xz4[4] = { bflo(gz.x), bfhi(gz.x), bflo(gz.y), bfhi(gz.y) };
        const float xn4[4] = { bflo(gn.x), bfhi(gn.x), bflo(gn.y), bfhi(gn.y) };

        short* hw = abuf + nxt * 4096 + koff;
        #pragma unroll
        for (int m = 0; m < 4; ++m) {
            float r_ = sigm(ar[m] + xr4[m]);          // b_hh(r,z) folded upstream
            float z_ = sigm(az[m] + xz4[m]);
            float n_ = tanh_(fmaf(r_, an[m], xn4[m])); // an = bhn + sum(h*wn)
            float h_ = fmaf(z_, hp[m] - n_, n_);
            hp[m] = h_;
            hw[m * 8] = (short)f2bf(h_);
        }
        __syncthreads();   // single per-step barrier
    }

    // ---- tail: FC for step ns-1, flush last 32, h carry ----
    if (wv == 0) {
        const short* ab = abuf + (ns & 1) * 4096;
        f32x4 afc = {0.f, 0.f, 0.f, 0.f};
        #pragma unroll
        for (int c = 0; c < 8; ++c)
            afc = mfma16(*(const bf16x8*)(ab + c * 512 + lane * 8),
                         *(const bf16x8*)(fcwl + c * 512 + lane * 8), afc);
        if (nn == 0) {
            const int s = ns - 1;
            f32x4 v;
            #pragma unroll
            for (int m = 0; m < 4; ++m) v[m] = afc[m] + fcb;
            *(f32x4*)(oring + (((s >> 5) & 1) << 9) + ((s & 31) << 4) + q * 4) = v;
        }
    }
    __syncthreads();
    if (tid < 512) {
        const int s0 = ns - 32;
        out[((size_t)(t0 + s0 + (tid >> 4))) * NB + bbase + (tid & 15)] =
            oring[(((s0 >> 5) & 1) << 9) + (tid >> 4) * 16 + (tid & 15)];
    }
    #pragma unroll
    for (int m = 0; m < 4; ++m)
        hcar[(size_t)(bbase + q * 4 + m) * NH + wv * 16 + nn] = hp[m];
}

extern "C" void kernel_launch(void* const* d_in, const int* in_sizes, int n_in,
                              void* d_out, int out_size, void* d_ws, size_t ws_size,
                              hipStream_t stream) {
    (void)in_sizes; (void)n_in; (void)out_size;
    const float* x    = (const float*)d_in[0];
    const float* w_ih = (const float*)d_in[1];
    const float* w_hh = (const float*)d_in[2];
    const float* b_ih = (const float*)d_in[3];
    const float* b_hh = (const float*)d_in[4];
    const float* fc_w = (const float*)d_in[5];
    const float* fc_b = (const float*)d_in[6];
    float* out  = (float*)d_out;
    float* hcar = (float*)d_ws;                       // 64 KB h carry
    short* xg   = (short*)((char*)d_ws + 65536);      // 3 gate planes

    const size_t per_step = (size_t)NB * 3 * NH * 2;  // 98304 B / step
    long avail = (long)ws_size - 65536;
    int spc = 64;
    if (avail >= (long)per_step * 64) {
        spc = (int)((avail / (long)per_step) / 64) * 64;
        if (spc > SEQ) spc = SEQ;
    }
    for (int t0 = 0; t0 < SEQ; t0 += spc) {
        int ns = (SEQ - t0 < spc) ? (SEQ - t0) : spc;
        size_t plane = (size_t)spc * 16384;           // shorts per gate plane
        xg_pre<<<dim3(2048), dim3(1024), 0, stream>>>(x, w_ih, b_ih, b_hh,
                                                      xg, plane, t0, ns);
        gru_rec<<<dim3(4), dim3(1024), 0, stream>>>(xg, plane, w_hh, b_hh,
                                                    fc_w, fc_b, out, hcar,
                                                    t0, ns);
    }
}

// Round 4
// 6839.083 us; speedup vs baseline: 3.0835x; 3.0835x over previous
//
#include <hip/hip_runtime.h>

#define SEQ  4096
#define NB   64
#define NI   64
#define NH   256

typedef short  bf16x8 __attribute__((ext_vector_type(8)));
typedef short  bf16x4 __attribute__((ext_vector_type(4)));
typedef float  f32x4  __attribute__((ext_vector_type(4)));

__device__ __forceinline__ unsigned short f2bf(float f) {
    union { float f; unsigned u; } v; v.f = f;
    return (unsigned short)((v.u + 0x7fffu + ((v.u >> 16) & 1u)) >> 16);
}
__device__ __forceinline__ float bflo(int p) {
    union { int i; float f; } u; u.i = p << 16; return u.f;
}
__device__ __forceinline__ float bfhi(int p) {
    union { int i; float f; } u; u.i = p & 0xffff0000; return u.f;
}
__device__ __forceinline__ float fast_rcp(float x) { return __builtin_amdgcn_rcpf(x); }
__device__ __forceinline__ float sigm(float x) { return fast_rcp(1.f + __expf(-x)); }
// clamp-free tanh: 2/(1+e^{-2y}) - 1.  y->+inf: e->0 -> +1; y->-inf: e->inf -> rcp->0 -> -1.
__device__ __forceinline__ float tanh_(float y) {
    float e = __expf(-2.f * y);
    return fmaf(2.f, fast_rcp(1.f + e), -1.f);
}
__device__ __forceinline__ f32x4 mfma16(bf16x8 a, bf16x8 b, f32x4 c) {
    return __builtin_amdgcn_mfma_f32_16x16x32_bf16(a, b, c, 0, 0, 0);
}
__device__ __forceinline__ bf16x8 ldfrag(const float* p) {
    float4 a = *(const float4*)p;
    float4 b = *(const float4*)(p + 4);
    bf16x8 r;
    r[0] = (short)f2bf(a.x); r[1] = (short)f2bf(a.y);
    r[2] = (short)f2bf(a.z); r[3] = (short)f2bf(a.w);
    r[4] = (short)f2bf(b.x); r[5] = (short)f2bf(b.y);
    r[6] = (short)f2bf(b.z); r[7] = (short)f2bf(b.w);
    return r;
}

// ============ xg precompute: LDS-free, barrier-free =========================
__global__ __launch_bounds__(1024) void xg_pre(
        const float* __restrict__ x, const float* __restrict__ w_ih,
        const float* __restrict__ b_ih, const float* __restrict__ b_hh,
        short* __restrict__ xg, size_t plane, int t0, int ns)
{
    const int tid = threadIdx.x, wv = tid >> 6, lane = tid & 63;
    const int nn = lane & 15, q = lane >> 4;
    const int jb = wv;

    bf16x8 w[3][2];
    float bias[3];
    #pragma unroll
    for (int g = 0; g < 3; ++g) {
        const int row = g * NH + jb * 16 + nn;
        w[g][0] = ldfrag(w_ih + row * NI + q * 8);
        w[g][1] = ldfrag(w_ih + row * NI + 32 + q * 8);
        bias[g] = b_ih[row] + (g < 2 ? b_hh[row] : 0.f);
    }

    const int NT = ns * 4;                       // 16-row tiles in chunk
    for (int rt = blockIdx.x; rt < NT; rt += gridDim.x) {
        const float* xr = x + ((size_t)t0 * NB + (size_t)rt * 16 + nn) * NI + q * 8;
        bf16x8 a0 = ldfrag(xr);
        bf16x8 a1 = ldfrag(xr + 32);
        #pragma unroll
        for (int g = 0; g < 3; ++g) {
            f32x4 acc = {0.f, 0.f, 0.f, 0.f};
            acc = mfma16(a0, w[g][0], acc);
            acc = mfma16(a1, w[g][1], acc);
            bf16x4 v;
            #pragma unroll
            for (int m = 0; m < 4; ++m) v[m] = (short)f2bf(acc[m] + bias[g]);
            *(bf16x4*)(xg + (size_t)g * plane +
                       (((size_t)rt * 16 + jb) * 64 + lane) * 4) = v;
        }
    }
}

// ============ recurrent kernel ==============================================
// Round-0 structure EXACTLY (proven 4353us gru_rec): 16 waves, wr/wz in regs
// (64), wn streamed from LDS, xg loaded at loop top and consumed AFTER the
// MFMA chain (lesson R2: consuming loads in MFMA C-init moves the vmcnt
// drain before the MFMA phase and exposes ~800cyc load latency), FC fused on
// a rotating wave. Only two decoupled VALU cuts added:
//   - clamp-free tanh (2*rcp(1+exp(-2y))-1), saturates correctly at +-inf
//   - b_hh(n) folded into the an accumulator C-init (SGPR broadcast, no wait)
// Lesson R3: all-3-gates-in-regs needs 96+~35 regs > 128 cap (16 waves force
// 4 waves/SIMD); the compiler remat's the loads into the loop at 3x cost.
// LDS: wlds 128K | abuf 16K | fcwl 8K | oring 4K = 156 KB.
__global__ __launch_bounds__(1024, 4) void gru_rec(
        const short* __restrict__ xg, size_t plane,
        const float* __restrict__ w_hh,
        const float* __restrict__ b_hh,
        const float* __restrict__ fc_w,
        const float* __restrict__ fc_b,
        float* __restrict__ out,
        float* __restrict__ hcar,
        int t0, int ns)
{
    __shared__ short wlds[65536];    // n-gate W_hh: 16 jb x 8 chunks x 512
    __shared__ short abuf[8192];     // h staging, 2 x 8 chunks x 512
    __shared__ short fcwl[4096];     // fc_w B-frags (col 0 only), 8 x 512
    __shared__ float oring[1024];    // out ring, 2 x 32 steps x 16 batch

    const int tid = threadIdx.x, wv = tid >> 6, lane = tid & 63;
    const int nn = lane & 15, q = lane >> 4;
    const int bc = blockIdx.x, bbase = bc * 16;

    // ---- one-time staging ----
    bf16x8 wr[8], wz[8];
    #pragma unroll
    for (int c = 0; c < 8; ++c)
        wr[c] = ldfrag(w_hh + (0 * NH + wv * 16 + nn) * NH + c * 32 + q * 8);
    #pragma unroll
    for (int c = 0; c < 8; ++c)
        wz[c] = ldfrag(w_hh + (1 * NH + wv * 16 + nn) * NH + c * 32 + q * 8);
    #pragma unroll
    for (int c = 0; c < 8; ++c) {
        bf16x8 f = ldfrag(w_hh + (2 * NH + wv * 16 + nn) * NH + c * 32 + q * 8);
        *(bf16x8*)(wlds + (wv * 8 + c) * 512 + lane * 8) = f;
    }
    if (wv < 8) {                    // fc B-frag: col nn==0 = fc_w, else 0
        bf16x8 f = 0;
        if (nn == 0) f = ldfrag(fc_w + wv * 32 + q * 8);
        *(bf16x8*)(fcwl + wv * 512 + lane * 8) = f;
    }
    const float bhn = b_hh[2 * NH + wv * 16 + nn];
    const float fcb = fc_b[0];

    // ---- h init ----
    f32x4 hp = {0.f, 0.f, 0.f, 0.f};
    if (t0 == 0) {
        ((int4*)abuf)[tid] = make_int4(0, 0, 0, 0);
    } else {
        #pragma unroll
        for (int m = 0; m < 4; ++m)
            hp[m] = hcar[(size_t)(bbase + q * 4 + m) * NH + wv * 16 + nn];
        const int f = tid * 4, b = f >> 8, k0 = f & 255;
        float4 v = *(const float4*)(hcar + (size_t)(bbase + b) * NH + k0);
        bf16x4 s; s[0] = (short)f2bf(v.x); s[1] = (short)f2bf(v.y);
        s[2] = (short)f2bf(v.z); s[3] = (short)f2bf(v.w);
        *(bf16x4*)(abuf + (k0 >> 5) * 512 + (((k0 >> 3) & 3) * 16 + b) * 8 + (k0 & 7)) = s;
    }

    const int j = wv * 16 + nn;
    const int koff = (j >> 5) * 512 + ((j >> 3) & 3) * 128 + (j & 7) + q * 32;
    const short* xgp = xg + ((size_t)(bc * 16 + wv) * 64 + lane) * 4;
    __syncthreads();

    for (int t = 0; t < ns; ++t) {
        const int cur = t & 1, nxt = cur ^ 1;

        int2 gx = *(const int2*)(xgp);
        int2 gz = *(const int2*)(xgp + plane);
        int2 gn = *(const int2*)(xgp + 2 * plane);
        xgp += 16384;

        // out flush, once per 32 steps (slots all >=1 barrier old)
        if ((t & 31) == 1 && t >= 33 && tid < 512) {
            const int s0 = t - 33;
            out[((size_t)(t0 + s0 + (tid >> 4))) * NB + bbase + (tid & 15)] =
                oring[(((s0 >> 5) & 1) << 9) + (tid >> 4) * 16 + (tid & 15)];
        }

        const bool isfc = (t > 0) && (wv == (t & 15));
        f32x4 ar = {0.f,0.f,0.f,0.f}, az = {0.f,0.f,0.f,0.f};
        f32x4 an = { bhn, bhn, bhn, bhn };   // b_hh(n) folded into C-init
        f32x4 afc = {0.f,0.f,0.f,0.f};
        const short* ab = abuf + cur * 4096;
        #pragma unroll
        for (int c = 0; c < 8; ++c) {
            bf16x8 av = *(const bf16x8*)(ab + c * 512 + lane * 8);
            ar = mfma16(av, wr[c], ar);
            az = mfma16(av, wz[c], az);
            bf16x8 wnf = *(const bf16x8*)(wlds + (wv * 8 + c) * 512 + lane * 8);
            an = mfma16(av, wnf, an);
            if (isfc) {   // rotating wave: FC(h_{t-1}) rides on the same av
                bf16x8 ff = *(const bf16x8*)(fcwl + c * 512 + lane * 8);
                afc = mfma16(av, ff, afc);
            }
        }
        if (isfc && nn == 0) {
            const int s = t - 1;
            f32x4 v;
            #pragma unroll
            for (int m = 0; m < 4; ++m) v[m] = afc[m] + fcb;
            *(f32x4*)(oring + (((s >> 5) & 1) << 9) + ((s & 31) << 4) + q * 4) = v;
        }

        const float xr4[4] = { bflo(gx.x), bfhi(gx.x), bflo(gx.y), bfhi(gx.y) };
        const float xz4[4] = { bflo(gz.x), bfhi(gz.x), bflo(gz.y), bfhi(gz.y) };
        const float xn4[4] = { bflo(gn.x), bfhi(gn.x), bflo(gn.y), bfhi(gn.y) };

        short* hw = abuf + nxt * 4096 + koff;
        #pragma unroll
        for (int m = 0; m < 4; ++m) {
            float r_ = sigm(ar[m] + xr4[m]);           // b_hh(r,z) folded upstream
            float z_ = sigm(az[m] + xz4[m]);
            float n_ = tanh_(fmaf(r_, an[m], xn4[m])); // an = bhn + sum(h*wn)
            float h_ = fmaf(z_, hp[m] - n_, n_);
            hp[m] = h_;
            hw[m * 8] = (short)f2bf(h_);
        }
        __syncthreads();   // single per-step barrier
    }

    // ---- tail: FC for step ns-1, flush last 32, h carry ----
    if (wv == 0) {
        const short* ab = abuf + (ns & 1) * 4096;
        f32x4 afc = {0.f, 0.f, 0.f, 0.f};
        #pragma unroll
        for (int c = 0; c < 8; ++c)
            afc = mfma16(*(const bf16x8*)(ab + c * 512 + lane * 8),
                         *(const bf16x8*)(fcwl + c * 512 + lane * 8), afc);
        if (nn == 0) {
            const int s = ns - 1;
            f32x4 v;
            #pragma unroll
            for (int m = 0; m < 4; ++m) v[m] = afc[m] + fcb;
            *(f32x4*)(oring + (((s >> 5) & 1) << 9) + ((s & 31) << 4) + q * 4) = v;
        }
    }
    __syncthreads();
    if (tid < 512) {
        const int s0 = ns - 32;
        out[((size_t)(t0 + s0 + (tid >> 4))) * NB + bbase + (tid & 15)] =
            oring[(((s0 >> 5) & 1) << 9) + (tid >> 4) * 16 + (tid & 15)];
    }
    #pragma unroll
    for (int m = 0; m < 4; ++m)
        hcar[(size_t)(bbase + q * 4 + m) * NH + wv * 16 + nn] = hp[m];
}

extern "C" void kernel_launch(void* const* d_in, const int* in_sizes, int n_in,
                              void* d_out, int out_size, void* d_ws, size_t ws_size,
                              hipStream_t stream) {
    (void)in_sizes; (void)n_in; (void)out_size;
    const float* x    = (const float*)d_in[0];
    const float* w_ih = (const float*)d_in[1];
    const float* w_hh = (const float*)d_in[2];
    const float* b_ih = (const float*)d_in[3];
    const float* b_hh = (const float*)d_in[4];
    const float* fc_w = (const float*)d_in[5];
    const float* fc_b = (const float*)d_in[6];
    float* out  = (float*)d_out;
    float* hcar = (float*)d_ws;                       // 64 KB h carry
    short* xg   = (short*)((char*)d_ws + 65536);      // 3 gate planes

    const size_t per_step = (size_t)NB * 3 * NH * 2;  // 98304 B / step
    long avail = (long)ws_size - 65536;
    int spc = 64;
    if (avail >= (long)per_step * 64) {
        spc = (int)((avail / (long)per_step) / 64) * 64;
        if (spc > SEQ) spc = SEQ;
    }
    for (int t0 = 0; t0 < SEQ; t0 += spc) {
        int ns = (SEQ - t0 < spc) ? (SEQ - t0) : spc;
        size_t plane = (size_t)spc * 16384;           // shorts per gate plane
        xg_pre<<<dim3(2048), dim3(1024), 0, stream>>>(x, w_ih, b_ih, b_hh,
                                                      xg, plane, t0, ns);
        gru_rec<<<dim3(4), dim3(1024), 0, stream>>>(xg, plane, w_hh, b_hh,
                                                    fc_w, fc_b, out, hcar,
                                                    t0, ns);
    }
}